// Round 5
// baseline (1101.894 us; speedup 1.0000x reference)
//
#include <hip/hip_runtime.h>
#include <hip/hip_bf16.h>
#include <math.h>

// Problem constants (Qwen3 MoE block)
#define T_TOK 2048
#define H_DIM 2048
#define NEXP  64
#define TOPK  8
#define I_DIM 768
#define CAPE  512
#define MTMAX 4     // CAPE/128
#define LDW   40    // LDS row stride in shorts (80B)
#define YROWS 24576 // compact-y row capacity (sum of ceil128(cnt))

typedef short bf16x8 __attribute__((ext_vector_type(8)));
typedef float f32x4  __attribute__((ext_vector_type(4)));

__device__ __forceinline__ unsigned short f2bf(float f) {
  unsigned u = __float_as_uint(f);
  u += 0x7fffu + ((u >> 16) & 1u);   // RNE
  return (unsigned short)(u >> 16);
}
__device__ __forceinline__ float bf2f(unsigned short b) {
  return __uint_as_float(((unsigned)b) << 16);
}
__device__ __forceinline__ unsigned pack2(float lo, float hi) {
  __hip_bfloat162 h = __float22bfloat162_rn(make_float2(lo, hi));  // v_cvt_pk_bf16_f32
  unsigned r; __builtin_memcpy(&r, &h, 4); return r;
}
// LDS-consistency barrier that does NOT drain vmcnt (keeps global prefetch in flight)
__device__ __forceinline__ void lds_barrier() {
  asm volatile("s_waitcnt lgkmcnt(0)" ::: "memory");
  __builtin_amdgcn_s_barrier();
  __builtin_amdgcn_sched_barrier(0);
}

// ---------------- K1: router logits + softmax-top8 + renorm ----------------
__global__ __launch_bounds__(256) void k_router(const float* __restrict__ x,
                                                const float* __restrict__ wr,
                                                int* __restrict__ topk_idx,
                                                float* __restrict__ topk_w) {
  const int lane = threadIdx.x & 63;
  const int t = blockIdx.x * 4 + (threadIdx.x >> 6);
  const float4* xr   = (const float4*)(x + (size_t)t * H_DIM);
  const float4* wrow = (const float4*)(wr + (size_t)lane * H_DIM);
  double acc = 0.0;                      // fp64: minimize top-k tie risk
  for (int i = 0; i < H_DIM / 4; ++i) {
    float4 a = xr[i], b = wrow[i];
    acc += (double)a.x * b.x; acc += (double)a.y * b.y;
    acc += (double)a.z * b.z; acc += (double)a.w * b.w;
  }
  float cur = (float)acc;
  float val[TOPK]; int idx[TOPK];
#pragma unroll
  for (int r = 0; r < TOPK; ++r) {
    float bv = cur; int bi = lane;
#pragma unroll
    for (int off = 32; off > 0; off >>= 1) {   // argmax, ties -> lower index
      float ov = __shfl_xor(bv, off);
      int   oi = __shfl_xor(bi, off);
      if (ov > bv || (ov == bv && oi < bi)) { bv = ov; bi = oi; }
    }
    val[r] = bv; idx[r] = bi;
    if (lane == bi) cur = -INFINITY;
  }
  float m = val[0], s = 0.f, w[TOPK];
#pragma unroll
  for (int r = 0; r < TOPK; ++r) { w[r] = expf(val[r] - m); s += w[r]; }
  if (lane < TOPK) {
    topk_idx[t * TOPK + lane] = idx[lane];
    topk_w [t * TOPK + lane] = w[lane] / s;
  }
}

// ---------------- K2: stable rank within expert + padded prefix ------------
__global__ __launch_bounds__(256) void k_rank(const int* __restrict__ topk_idx,
                                              int* __restrict__ pair_pos,
                                              int* __restrict__ slot_token,
                                              int* __restrict__ cnts,
                                              int* __restrict__ pstart) {
  __shared__ int s_run[64];
  __shared__ int s_whist[4][64];
  const int tid = threadIdx.x, lane = tid & 63, wv = tid >> 6;
  if (tid < 64) s_run[tid] = 0;
  for (int c = 0; c < 64; ++c) {
    const int p = c * 256 + tid;
    const int e = topk_idx[p];
    __syncthreads();
    s_whist[wv][lane] = 0;
    __syncthreads();
    unsigned long long m = ~0ull;
#pragma unroll
    for (int b = 0; b < 6; ++b) {
      unsigned long long bb = __ballot((e >> b) & 1);
      m &= ((e >> b) & 1) ? bb : ~bb;
    }
    const int rw = __popcll(m & ((1ull << lane) - 1ull));
    if (rw == 0) s_whist[wv][e] = __popcll(m);
    __syncthreads();
    int r = rw;
    for (int w2 = 0; w2 < wv; ++w2) r += s_whist[w2][e];
    const int pos = s_run[e] + r;
    pair_pos[p] = pos;
    if (pos < CAPE) slot_token[e * CAPE + pos] = p >> 3;
    __syncthreads();
    if (tid < 64)
      s_run[tid] += s_whist[0][tid] + s_whist[1][tid] + s_whist[2][tid] + s_whist[3][tid];
  }
  __syncthreads();
  if (tid < 64) cnts[tid] = s_run[tid];
  if (tid == 0) {
    int run = 0;
    for (int ee = 0; ee < 64; ++ee) {
      pstart[ee] = run;
      int c = s_run[ee]; if (c > CAPE) c = CAPE;
      run += (c + 127) & ~127;
    }
    pstart[64] = run;
  }
}

// ---------------- K3: mm1 = X @ {Wg|Wu} -> gbuf/ubuf (bf16) ----------------
// grid = E*MTMAX*12; block = 256 (4 waves 2x2), tile 128x128, wave tile 64x64.
// Step order LOAD->COMPUTE->STORE + no-drain barrier => steady-state vmcnt(8).
__global__ __launch_bounds__(256, 3) void k_mm1(const float* __restrict__ x,
                                                const float* __restrict__ wg,
                                                const float* __restrict__ wu,
                                                const int* __restrict__ slot_token,
                                                const int* __restrict__ cnts,
                                                unsigned short* __restrict__ gbuf,
                                                unsigned short* __restrict__ ubuf) {
  const int NB = NEXP * MTMAX * 12;
  const int v = (blockIdx.x & 7) * (NB / 8) + (blockIdx.x >> 3);  // XCD chunk swizzle
  const int mt = v & 3;              // mt fastest: B-panel siblings co-resident
  const int nti = (v >> 2) % 12;
  const int e = v / 48;

  int cnt = cnts[e]; cnt = cnt < CAPE ? cnt : CAPE;
  if (cnt <= 0 || mt * 128 >= cnt) return;
  const int m0 = mt << 7;
  const float* wsrc = (nti < 6) ? wg : wu;
  unsigned short* obuf = (nti < 6) ? gbuf : ubuf;
  const int ncol = (nti % 6) * 128;

  __shared__ __align__(16) short As[2][128 * LDW];   // 10 KiB each
  __shared__ __align__(16) short Bs[2][128 * LDW];

  const int tid = threadIdx.x;
  const int lane = tid & 63, wave = tid >> 6;
  const int wm = wave >> 1, wn = wave & 1;       // 2x2 waves, 64x64 tiles
  const int lr = lane & 15, lg = lane >> 4;

  const int a_row = tid >> 1, a_half = tid & 1;  // A: row 0..127, 16-float half
  const int b_kp = tid & 15;                     // B: k-pair, two col-quads
  const int b_nq0 = tid >> 4, b_nq1 = b_nq0 + 16;
  const size_t wbase = (size_t)e * H_DIM * I_DIM + (size_t)ncol;

  const int tok = (m0 + a_row < cnt) ? slot_token[e * CAPE + m0 + a_row] : 0;
  const float* xr = x + (size_t)tok * H_DIM + a_half * 16;
  const float* bp = wsrc + wbase + (size_t)(2 * b_kp) * I_DIM;

  f32x4 acc[4][4];
#pragma unroll
  for (int mi = 0; mi < 4; ++mi)
#pragma unroll
    for (int ni = 0; ni < 4; ++ni) acc[mi][ni] = (f32x4){0.f, 0.f, 0.f, 0.f};

  struct Tile { float4 a[4]; float4 b0[2]; float4 b1[2]; };
  Tile tA, tB;

  auto LOAD = [&](Tile& T, int kt) {
    const int k0 = kt * 32;
#pragma unroll
    for (int j = 0; j < 4; ++j) T.a[j] = *(const float4*)(xr + k0 + j * 4);
    const float* r0 = bp + (size_t)k0 * I_DIM;
    T.b0[0] = *(const float4*)(r0 + 4 * b_nq0);
    T.b0[1] = *(const float4*)(r0 + I_DIM + 4 * b_nq0);
    T.b1[0] = *(const float4*)(r0 + 4 * b_nq1);
    T.b1[1] = *(const float4*)(r0 + I_DIM + 4 * b_nq1);
    __builtin_amdgcn_sched_barrier(0);   // pin issue point: loads stay ABOVE compute/store
  };
  auto STORE = [&](const Tile& T, int b) {
    uint4 w0 = { pack2(T.a[0].x, T.a[0].y), pack2(T.a[0].z, T.a[0].w),
                 pack2(T.a[1].x, T.a[1].y), pack2(T.a[1].z, T.a[1].w) };
    uint4 w1 = { pack2(T.a[2].x, T.a[2].y), pack2(T.a[2].z, T.a[2].w),
                 pack2(T.a[3].x, T.a[3].y), pack2(T.a[3].z, T.a[3].w) };
    *(uint4*)(&As[b][a_row * LDW + a_half * 16])     = w0;
    *(uint4*)(&As[b][a_row * LDW + a_half * 16 + 8]) = w1;
    *(unsigned*)(&Bs[b][(4 * b_nq0 + 0) * LDW + 2 * b_kp]) = pack2(T.b0[0].x, T.b0[1].x);
    *(unsigned*)(&Bs[b][(4 * b_nq0 + 1) * LDW + 2 * b_kp]) = pack2(T.b0[0].y, T.b0[1].y);
    *(unsigned*)(&Bs[b][(4 * b_nq0 + 2) * LDW + 2 * b_kp]) = pack2(T.b0[0].z, T.b0[1].z);
    *(unsigned*)(&Bs[b][(4 * b_nq0 + 3) * LDW + 2 * b_kp]) = pack2(T.b0[0].w, T.b0[1].w);
    *(unsigned*)(&Bs[b][(4 * b_nq1 + 0) * LDW + 2 * b_kp]) = pack2(T.b1[0].x, T.b1[1].x);
    *(unsigned*)(&Bs[b][(4 * b_nq1 + 1) * LDW + 2 * b_kp]) = pack2(T.b1[0].y, T.b1[1].y);
    *(unsigned*)(&Bs[b][(4 * b_nq1 + 2) * LDW + 2 * b_kp]) = pack2(T.b1[0].z, T.b1[1].z);
    *(unsigned*)(&Bs[b][(4 * b_nq1 + 3) * LDW + 2 * b_kp]) = pack2(T.b1[0].w, T.b1[1].w);
  };
  auto COMPUTE = [&](int b) {
    bf16x8 af[4], bf[4];
#pragma unroll
    for (int mi = 0; mi < 4; ++mi)
      af[mi] = *(const bf16x8*)(&As[b][(wm * 64 + mi * 16 + lr) * LDW + lg * 8]);
#pragma unroll
    for (int ni = 0; ni < 4; ++ni)
      bf[ni] = *(const bf16x8*)(&Bs[b][(wn * 64 + ni * 16 + lr) * LDW + lg * 8]);
    __builtin_amdgcn_s_setprio(1);
#pragma unroll
    for (int mi = 0; mi < 4; ++mi)
#pragma unroll
      for (int ni = 0; ni < 4; ++ni)
        acc[mi][ni] = __builtin_amdgcn_mfma_f32_16x16x32_bf16(af[mi], bf[ni], acc[mi][ni], 0, 0, 0);
    __builtin_amdgcn_s_setprio(0);
  };

  const int NK = H_DIM / 32;   // 64, even
  LOAD(tA, 0); LOAD(tB, 1);
  STORE(tA, 0);                 // waits vmcnt(8): tB stays in flight
  lds_barrier();

#pragma unroll 1
  for (int t = 0; t + 3 < NK; t += 2) {
    LOAD(tA, t + 2);            // tA freed by last STORE; issue before any wait
    COMPUTE(0);
    STORE(tB, 1);               // vmcnt(8): tA's loads remain outstanding
    lds_barrier();
    LOAD(tB, t + 3);
    COMPUTE(1);
    STORE(tA, 0);
    lds_barrier();
  }
  COMPUTE(0);                   // tile NK-2
  STORE(tB, 1);                 // tile NK-1
  lds_barrier();
  COMPUTE(1);

#pragma unroll
  for (int mi = 0; mi < 4; ++mi)
#pragma unroll
    for (int ni = 0; ni < 4; ++ni)
#pragma unroll
      for (int r = 0; r < 4; ++r) {
        const int row = m0 + wm * 64 + mi * 16 + lg * 4 + r;
        const int col = ncol + wn * 64 + ni * 16 + lr;
        obuf[(size_t)(e * CAPE + row) * I_DIM + col] = f2bf(acc[mi][ni][r]);
      }
}

// ---------------- K4: act = silu(g) * u, in-place into gbuf ----------------
__global__ __launch_bounds__(256) void k_act(unsigned short* __restrict__ gbuf,
                                             const unsigned short* __restrict__ ubuf,
                                             const int* __restrict__ cnts) {
  const int e = blockIdx.x >> 6;
  const int r0 = (blockIdx.x & 63) * 8;
  int cnt = cnts[e]; cnt = cnt < CAPE ? cnt : CAPE;
  const int lim = (cnt + 127) & ~127;
  if (r0 >= lim) return;
#pragma unroll
  for (int s = 0; s < 3; ++s) {
    const int c = threadIdx.x + 256 * s;
    const int row = r0 + c / 96;
    const int col = (c % 96) * 8;
    const size_t idx = (size_t)(e * CAPE + row) * I_DIM + col;
    bf16x8 g8 = *(const bf16x8*)(gbuf + idx);
    bf16x8 u8 = *(const bf16x8*)(ubuf + idx);
    bf16x8 o;
#pragma unroll
    for (int j = 0; j < 8; ++j) {
      const float g = bf2f((unsigned short)g8[j]);
      const float u = bf2f((unsigned short)u8[j]);
      o[j] = (short)f2bf((g / (1.f + __expf(-g))) * u);
    }
    *(bf16x8*)(gbuf + idx) = o;
  }
}

// ---------------- K5: down GEMM -> y (bf16, compact rows) ------------------
// grid = E*MTMAX*16; block = 256 (4 waves 2x2). Same pipeline as mm1.
__global__ __launch_bounds__(256, 3) void k_down(const unsigned short* __restrict__ act,
                                                 const float* __restrict__ wd,
                                                 const int* __restrict__ cnts,
                                                 const int* __restrict__ pstart,
                                                 unsigned short* __restrict__ y) {
  const int NB = NEXP * MTMAX * 16;
  const int v = (blockIdx.x & 7) * (NB / 8) + (blockIdx.x >> 3);
  const int mt = v & 3;              // mt fastest: B-panel siblings co-resident
  const int nt = (v >> 2) & 15;
  const int e = v >> 6;

  int cnt = cnts[e]; cnt = cnt < CAPE ? cnt : CAPE;
  if (cnt <= 0 || mt * 128 >= cnt) return;
  const int m0 = mt << 7;
  const int ybase = pstart[e];
  if (ybase + m0 + 128 > YROWS) return;   // never in practice

  __shared__ __align__(16) short As[2][128 * LDW];
  __shared__ __align__(16) short Bs[2][128 * LDW];

  const int tid = threadIdx.x;
  const int lane = tid & 63, wave = tid >> 6;
  const int wm = wave >> 1, wn = wave & 1;
  const int lr = lane & 15, lg = lane >> 4;

  const int a_row = tid >> 1, a_half = tid & 1;
  const int b_kp = tid & 15;
  const int b_nq0 = tid >> 4, b_nq1 = b_nq0 + 16;
  const size_t wbase = (size_t)e * I_DIM * H_DIM + (size_t)nt * 128;

  const unsigned short* ap = act + (size_t)(e * CAPE + m0 + a_row) * I_DIM + a_half * 16;
  const float* bp = wd + wbase + (size_t)(2 * b_kp) * H_DIM;

  f32x4 acc[4][4];
#pragma unroll
  for (int mi = 0; mi < 4; ++mi)
#pragma unroll
    for (int ni = 0; ni < 4; ++ni) acc[mi][ni] = (f32x4){0.f, 0.f, 0.f, 0.f};

  struct Tile { bf16x8 a[2]; float4 b0[2]; float4 b1[2]; };
  Tile tA, tB;

  auto LOAD = [&](Tile& T, int kt) {
    const int k0 = kt * 32;
    T.a[0] = *(const bf16x8*)(ap + k0);
    T.a[1] = *(const bf16x8*)(ap + k0 + 8);
    const float* r0 = bp + (size_t)k0 * H_DIM;
    T.b0[0] = *(const float4*)(r0 + 4 * b_nq0);
    T.b0[1] = *(const float4*)(r0 + H_DIM + 4 * b_nq0);
    T.b1[0] = *(const float4*)(r0 + 4 * b_nq1);
    T.b1[1] = *(const float4*)(r0 + H_DIM + 4 * b_nq1);
    __builtin_amdgcn_sched_barrier(0);
  };
  auto STORE = [&](const Tile& T, int b) {
    *(bf16x8*)(&As[b][a_row * LDW + a_half * 16])     = T.a[0];
    *(bf16x8*)(&As[b][a_row * LDW + a_half * 16 + 8]) = T.a[1];
    *(unsigned*)(&Bs[b][(4 * b_nq0 + 0) * LDW + 2 * b_kp]) = pack2(T.b0[0].x, T.b0[1].x);
    *(unsigned*)(&Bs[b][(4 * b_nq0 + 1) * LDW + 2 * b_kp]) = pack2(T.b0[0].y, T.b0[1].y);
    *(unsigned*)(&Bs[b][(4 * b_nq0 + 2) * LDW + 2 * b_kp]) = pack2(T.b0[0].z, T.b0[1].z);
    *(unsigned*)(&Bs[b][(4 * b_nq0 + 3) * LDW + 2 * b_kp]) = pack2(T.b0[0].w, T.b0[1].w);
    *(unsigned*)(&Bs[b][(4 * b_nq1 + 0) * LDW + 2 * b_kp]) = pack2(T.b1[0].x, T.b1[1].x);
    *(unsigned*)(&Bs[b][(4 * b_nq1 + 1) * LDW + 2 * b_kp]) = pack2(T.b1[0].y, T.b1[1].y);
    *(unsigned*)(&Bs[b][(4 * b_nq1 + 2) * LDW + 2 * b_kp]) = pack2(T.b1[0].z, T.b1[1].z);
    *(unsigned*)(&Bs[b][(4 * b_nq1 + 3) * LDW + 2 * b_kp]) = pack2(T.b1[0].w, T.b1[1].w);
  };
  auto COMPUTE = [&](int b) {
    bf16x8 af[4], bf[4];
#pragma unroll
    for (int mi = 0; mi < 4; ++mi)
      af[mi] = *(const bf16x8*)(&As[b][(wm * 64 + mi * 16 + lr) * LDW + lg * 8]);
#pragma unroll
    for (int ni = 0; ni < 4; ++ni)
      bf[ni] = *(const bf16x8*)(&Bs[b][(wn * 64 + ni * 16 + lr) * LDW + lg * 8]);
    __builtin_amdgcn_s_setprio(1);
#pragma unroll
    for (int mi = 0; mi < 4; ++mi)
#pragma unroll
      for (int ni = 0; ni < 4; ++ni)
        acc[mi][ni] = __builtin_amdgcn_mfma_f32_16x16x32_bf16(af[mi], bf[ni], acc[mi][ni], 0, 0, 0);
    __builtin_amdgcn_s_setprio(0);
  };

  const int NK = I_DIM / 32;   // 24, even
  LOAD(tA, 0); LOAD(tB, 1);
  STORE(tA, 0);
  lds_barrier();

#pragma unroll 1
  for (int t = 0; t + 3 < NK; t += 2) {
    LOAD(tA, t + 2);
    COMPUTE(0);
    STORE(tB, 1);
    lds_barrier();
    LOAD(tB, t + 3);
    COMPUTE(1);
    STORE(tA, 0);
    lds_barrier();
  }
  COMPUTE(0);
  STORE(tB, 1);
  lds_barrier();
  COMPUTE(1);

#pragma unroll
  for (int mi = 0; mi < 4; ++mi)
#pragma unroll
    for (int ni = 0; ni < 4; ++ni)
#pragma unroll
      for (int r = 0; r < 4; ++r) {
        const int row = ybase + m0 + wm * 64 + mi * 16 + lg * 4 + r;
        const int col = nt * 128 + wn * 64 + ni * 16 + lr;
        y[(size_t)row * H_DIM + col] = f2bf(acc[mi][ni][r]);
      }
}

// ---------------- K6: combine (deterministic gather) -----------------------
__global__ __launch_bounds__(256) void k_combine(const unsigned short* __restrict__ y,
                                                 const int* __restrict__ topk_idx,
                                                 const float* __restrict__ topk_w,
                                                 const int* __restrict__ pair_pos,
                                                 const int* __restrict__ pstart,
                                                 float* __restrict__ out) {
  const int t = blockIdx.x;
  __shared__ int s_r[TOPK]; __shared__ float s_w[TOPK];
  if (threadIdx.x < TOPK) {
    const int e = topk_idx[t * TOPK + threadIdx.x];
    const int pos = pair_pos[t * TOPK + threadIdx.x];
    const int row = pstart[e] + pos;
    s_r[threadIdx.x] = (pos < CAPE && row < YROWS) ? row : -1;
    s_w[threadIdx.x] = topk_w[t * TOPK + threadIdx.x];
  }
  __syncthreads();
  const int h0 = threadIdx.x * 8;
  float acc[8] = {0.f, 0.f, 0.f, 0.f, 0.f, 0.f, 0.f, 0.f};
#pragma unroll
  for (int k = 0; k < TOPK; ++k) {
    const int row = s_r[k];
    if (row < 0) continue;
    const float w = s_w[k];
    const bf16x8 vv = *(const bf16x8*)(&y[(size_t)row * H_DIM + h0]);
#pragma unroll
    for (int j = 0; j < 8; ++j) acc[j] += w * bf2f((unsigned short)vv[j]);
  }
  float4 o0 = {acc[0], acc[1], acc[2], acc[3]};
  float4 o1 = {acc[4], acc[5], acc[6], acc[7]};
  *(float4*)(out + (size_t)t * H_DIM + h0)     = o0;
  *(float4*)(out + (size_t)t * H_DIM + h0 + 4) = o1;
}

// ---------------------------------------------------------------------------
extern "C" void kernel_launch(void* const* d_in, const int* in_sizes, int n_in,
                              void* d_out, int out_size, void* d_ws, size_t ws_size,
                              hipStream_t stream) {
  const float* x   = (const float*)d_in[0];
  const float* wr  = (const float*)d_in[1];
  const float* wgt = (const float*)d_in[2];
  const float* wup = (const float*)d_in[3];
  const float* wdn = (const float*)d_in[4];
  float* out = (float*)d_out;

  char* ws = (char*)d_ws;
  int*            topk_idx   = (int*)(ws);                    //  64 KiB
  float*          topk_w     = (float*)(ws + 65536);
  int*            pair_pos   = (int*)(ws + 131072);
  int*            cnts       = (int*)(ws + 196608);           // 256 B
  int*            pstart     = (int*)(ws + 196864);           // 260 B
  int*            slot_token = (int*)(ws + 197376);           // 128 KiB
  unsigned short* gbuf       = (unsigned short*)(ws + 524288);             // 48 MiB (becomes act)
  unsigned short* ubuf       = (unsigned short*)(ws + 524288 + 50331648);  // 48 MiB
  // y overlays ubuf (dead after k_act) and extends beyond: 96 MiB
  unsigned short* yb         = (unsigned short*)(ws + 524288 + 50331648);

  k_router <<<dim3(T_TOK / 4),         dim3(256), 0, stream>>>(x, wr, topk_idx, topk_w);
  k_rank   <<<dim3(1),                 dim3(256), 0, stream>>>(topk_idx, pair_pos, slot_token, cnts, pstart);
  k_mm1    <<<dim3(NEXP * MTMAX * 12), dim3(256), 0, stream>>>(x, wgt, wup, slot_token, cnts, gbuf, ubuf);
  k_act    <<<dim3(NEXP * 64),         dim3(256), 0, stream>>>(gbuf, ubuf, cnts);
  k_down   <<<dim3(NEXP * MTMAX * 16), dim3(256), 0, stream>>>(gbuf, wdn, cnts, pstart, yb);
  k_combine<<<dim3(T_TOK),             dim3(256), 0, stream>>>(yb, topk_idx, topk_w, pair_pos, pstart, out);
}

// Round 6
// 905.109 us; speedup vs baseline: 1.2174x; 1.2174x over previous
//
#include <hip/hip_runtime.h>
#include <hip/hip_bf16.h>
#include <math.h>

// Problem constants (Qwen3 MoE block)
#define T_TOK 2048
#define H_DIM 2048
#define NEXP  64
#define TOPK  8
#define I_DIM 768
#define CAPE  512
#define MTMAX 4   // CAPE/128
#define LDW   40  // LDS row stride in shorts (80B)

typedef short bf16x8 __attribute__((ext_vector_type(8)));
typedef float f32x4  __attribute__((ext_vector_type(4)));

__device__ __forceinline__ unsigned short f2bf(float f) {
  unsigned u = __float_as_uint(f);
  u += 0x7fffu + ((u >> 16) & 1u);   // RNE
  return (unsigned short)(u >> 16);
}
__device__ __forceinline__ float bf2f(unsigned short b) {
  return __uint_as_float(((unsigned)b) << 16);
}
__device__ __forceinline__ unsigned pack2(float lo, float hi) {
  __hip_bfloat162 h = __float22bfloat162_rn(make_float2(lo, hi));  // v_cvt_pk_bf16_f32
  unsigned r; __builtin_memcpy(&r, &h, 4); return r;
}
// LDS-consistency barrier that does NOT drain vmcnt: in-flight global loads
// (targeting private registers) survive across the barrier. No sched_barrier,
// no setprio — let the compiler schedule (m141/m190 lessons).
__device__ __forceinline__ void lds_barrier() {
  asm volatile("s_waitcnt lgkmcnt(0)" ::: "memory");
  __builtin_amdgcn_s_barrier();
}

// ---------------- K1: router logits + softmax-top8 + renorm ----------------
__global__ __launch_bounds__(256) void k_router(const float* __restrict__ x,
                                                const float* __restrict__ wr,
                                                int* __restrict__ topk_idx,
                                                float* __restrict__ topk_w) {
  const int lane = threadIdx.x & 63;
  const int t = blockIdx.x * 4 + (threadIdx.x >> 6);
  const float4* xr   = (const float4*)(x + (size_t)t * H_DIM);
  const float4* wrow = (const float4*)(wr + (size_t)lane * H_DIM);
  double acc = 0.0;                      // fp64: minimize top-k tie risk
  for (int i = 0; i < H_DIM / 4; ++i) {
    float4 a = xr[i], b = wrow[i];
    acc += (double)a.x * b.x; acc += (double)a.y * b.y;
    acc += (double)a.z * b.z; acc += (double)a.w * b.w;
  }
  float cur = (float)acc;
  float val[TOPK]; int idx[TOPK];
#pragma unroll
  for (int r = 0; r < TOPK; ++r) {
    float bv = cur; int bi = lane;
#pragma unroll
    for (int off = 32; off > 0; off >>= 1) {   // argmax, ties -> lower index
      float ov = __shfl_xor(bv, off);
      int   oi = __shfl_xor(bi, off);
      if (ov > bv || (ov == bv && oi < bi)) { bv = ov; bi = oi; }
    }
    val[r] = bv; idx[r] = bi;
    if (lane == bi) cur = -INFINITY;
  }
  float m = val[0], s = 0.f, w[TOPK];
#pragma unroll
  for (int r = 0; r < TOPK; ++r) { w[r] = expf(val[r] - m); s += w[r]; }
  if (lane < TOPK) {
    topk_idx[t * TOPK + lane] = idx[lane];
    topk_w [t * TOPK + lane] = w[lane] / s;
  }
}

// ---------------- K2: stable rank within expert ----------------------------
__global__ __launch_bounds__(256) void k_rank(const int* __restrict__ topk_idx,
                                              int* __restrict__ pair_pos,
                                              int* __restrict__ slot_token,
                                              int* __restrict__ cnts) {
  __shared__ int s_run[64];
  __shared__ int s_whist[4][64];
  const int tid = threadIdx.x, lane = tid & 63, wv = tid >> 6;
  if (tid < 64) s_run[tid] = 0;
  for (int c = 0; c < 64; ++c) {
    const int p = c * 256 + tid;
    const int e = topk_idx[p];
    __syncthreads();
    s_whist[wv][lane] = 0;
    __syncthreads();
    unsigned long long m = ~0ull;
#pragma unroll
    for (int b = 0; b < 6; ++b) {
      unsigned long long bb = __ballot((e >> b) & 1);
      m &= ((e >> b) & 1) ? bb : ~bb;
    }
    const int rw = __popcll(m & ((1ull << lane) - 1ull));
    if (rw == 0) s_whist[wv][e] = __popcll(m);
    __syncthreads();
    int r = rw;
    for (int w2 = 0; w2 < wv; ++w2) r += s_whist[w2][e];
    const int pos = s_run[e] + r;
    pair_pos[p] = pos;
    if (pos < CAPE) slot_token[e * CAPE + pos] = p >> 3;
    __syncthreads();
    if (tid < 64)
      s_run[tid] += s_whist[0][tid] + s_whist[1][tid] + s_whist[2][tid] + s_whist[3][tid];
  }
  __syncthreads();
  if (tid < 64) cnts[tid] = s_run[tid];
}

// ---------------- K3: fused gate+up GEMM + SwiGLU -> act (bf16) ------------
// grid = E*MTMAX*6; block = 512 (8 waves, 2x4). LDS dbuf + 2-deep reg rotation,
// ONE lgkm-only barrier per k-step => prefetch survives the barrier (vmcnt(8)).
__global__ __launch_bounds__(512) void k_gateup(const float* __restrict__ x,
                                                const float* __restrict__ wg,
                                                const float* __restrict__ wu,
                                                const int* __restrict__ slot_token,
                                                const int* __restrict__ cnts,
                                                unsigned short* __restrict__ act) {
  const int NB = NEXP * MTMAX * 6;
  const int v = (blockIdx.x & 7) * (NB / 8) + (blockIdx.x >> 3);  // XCD chunk swizzle
  const int e = v / (MTMAX * 6);
  const int rem = v % (MTMAX * 6);
  const int mt = rem / 6, nt = rem % 6;

  int cnt = cnts[e]; cnt = cnt < CAPE ? cnt : CAPE;
  if (cnt <= 0 || mt * 128 >= cnt) return;
  const int m0 = mt << 7;

  __shared__ __align__(16) short As[2][128 * LDW];   // 20 KiB
  __shared__ __align__(16) short Bg[2][128 * LDW];   // 20 KiB
  __shared__ __align__(16) short Bu[2][128 * LDW];   // 20 KiB

  const int tid = threadIdx.x;
  const int lane = tid & 63, wave = tid >> 6;
  const int wm = wave >> 2, wn = wave & 3;       // 2x4 wave grid, 64x32 tiles
  const int lr = lane & 15, lg = lane >> 4;

  // A staging: rows tid>>3 and +64, col-quad tid&7
  const int a_row0 = tid >> 3, a_kq = tid & 7;
  const int a_row1 = a_row0 + 64;
  // B staging: kp = tid&15 (k-pair), nq = tid>>4 (n-quad)
  const int b_kp = tid & 15, b_nq = tid >> 4;
  const int bk = 2 * b_kp, bn = 4 * b_nq;
  const size_t wbase = (size_t)e * H_DIM * I_DIM + (size_t)nt * 128;

  const int tok0 = (m0 + a_row0 < cnt) ? slot_token[e * CAPE + m0 + a_row0] : 0;
  const int tok1 = (m0 + a_row1 < cnt) ? slot_token[e * CAPE + m0 + a_row1] : 0;
  const float* xr0 = x + (size_t)tok0 * H_DIM + a_kq * 4;
  const float* xr1 = x + (size_t)tok1 * H_DIM + a_kq * 4;
  const float* gp  = wg + wbase + (size_t)bk * I_DIM + bn;
  const float* up  = wu + wbase + (size_t)bk * I_DIM + bn;

  f32x4 accg[4][2], accu[4][2];
#pragma unroll
  for (int mi = 0; mi < 4; ++mi)
#pragma unroll
    for (int ni = 0; ni < 2; ++ni) {
      accg[mi][ni] = (f32x4){0.f, 0.f, 0.f, 0.f};
      accu[mi][ni] = (f32x4){0.f, 0.f, 0.f, 0.f};
    }

  struct Tile { float4 a0, a1, g0, g1, u0, u1; };

  auto LOAD = [&](Tile& Tl, int kt) {
    const int k0 = kt * 32;
    Tl.a0 = *(const float4*)(xr0 + k0);
    Tl.a1 = *(const float4*)(xr1 + k0);
    Tl.g0 = *(const float4*)(gp + (size_t)k0 * I_DIM);
    Tl.g1 = *(const float4*)(gp + (size_t)k0 * I_DIM + I_DIM);
    Tl.u0 = *(const float4*)(up + (size_t)k0 * I_DIM);
    Tl.u1 = *(const float4*)(up + (size_t)k0 * I_DIM + I_DIM);
  };
  auto STORE = [&](const Tile& Tl, int b) {
    *(unsigned*)(&As[b][a_row0 * LDW + a_kq * 4])     = pack2(Tl.a0.x, Tl.a0.y);
    *(unsigned*)(&As[b][a_row0 * LDW + a_kq * 4 + 2]) = pack2(Tl.a0.z, Tl.a0.w);
    *(unsigned*)(&As[b][a_row1 * LDW + a_kq * 4])     = pack2(Tl.a1.x, Tl.a1.y);
    *(unsigned*)(&As[b][a_row1 * LDW + a_kq * 4 + 2]) = pack2(Tl.a1.z, Tl.a1.w);
    *(unsigned*)(&Bg[b][(bn + 0) * LDW + bk]) = pack2(Tl.g0.x, Tl.g1.x);
    *(unsigned*)(&Bg[b][(bn + 1) * LDW + bk]) = pack2(Tl.g0.y, Tl.g1.y);
    *(unsigned*)(&Bg[b][(bn + 2) * LDW + bk]) = pack2(Tl.g0.z, Tl.g1.z);
    *(unsigned*)(&Bg[b][(bn + 3) * LDW + bk]) = pack2(Tl.g0.w, Tl.g1.w);
    *(unsigned*)(&Bu[b][(bn + 0) * LDW + bk]) = pack2(Tl.u0.x, Tl.u1.x);
    *(unsigned*)(&Bu[b][(bn + 1) * LDW + bk]) = pack2(Tl.u0.y, Tl.u1.y);
    *(unsigned*)(&Bu[b][(bn + 2) * LDW + bk]) = pack2(Tl.u0.z, Tl.u1.z);
    *(unsigned*)(&Bu[b][(bn + 3) * LDW + bk]) = pack2(Tl.u0.w, Tl.u1.w);
  };
  auto COMPUTE = [&](int b) {
    bf16x8 a[4], bg[2], bu[2];
#pragma unroll
    for (int mi = 0; mi < 4; ++mi)
      a[mi] = *(const bf16x8*)(&As[b][(wm * 64 + mi * 16 + lr) * LDW + lg * 8]);
#pragma unroll
    for (int ni = 0; ni < 2; ++ni) {
      bg[ni] = *(const bf16x8*)(&Bg[b][(wn * 32 + ni * 16 + lr) * LDW + lg * 8]);
      bu[ni] = *(const bf16x8*)(&Bu[b][(wn * 32 + ni * 16 + lr) * LDW + lg * 8]);
    }
#pragma unroll
    for (int mi = 0; mi < 4; ++mi)
#pragma unroll
      for (int ni = 0; ni < 2; ++ni) {
        accg[mi][ni] = __builtin_amdgcn_mfma_f32_16x16x32_bf16(a[mi], bg[ni], accg[mi][ni], 0, 0, 0);
        accu[mi][ni] = __builtin_amdgcn_mfma_f32_16x16x32_bf16(a[mi], bu[ni], accu[mi][ni], 0, 0, 0);
      }
  };

  const int NK = H_DIM / 32;   // 64, even
  Tile tA, tB;
  LOAD(tA, 0);
  STORE(tA, 0);                 // reg deps wait only tA's loads
  LOAD(tB, 1);
  lds_barrier();

  int t = 0;
#pragma unroll 1
  for (; t + 2 < NK; t += 2) {
    LOAD(tA, t + 2);            // in flight across the next barrier
    COMPUTE(0);                 // tile t
    STORE(tB, 1);               // vmcnt(8): tA's loads stay outstanding
    lds_barrier();
    LOAD(tB, t + 3);
    COMPUTE(1);                 // tile t+1
    STORE(tA, 0);               // tile t+2 -> buf0
    lds_barrier();
  }
  COMPUTE(0);                   // tile NK-2
  STORE(tB, 1);                 // tile NK-1
  lds_barrier();
  COMPUTE(1);                   // tile NK-1

  // epilogue: silu(g)*u -> bf16 act
#pragma unroll
  for (int mi = 0; mi < 4; ++mi)
#pragma unroll
    for (int ni = 0; ni < 2; ++ni)
#pragma unroll
      for (int r = 0; r < 4; ++r) {
        const int row = m0 + wm * 64 + mi * 16 + lg * 4 + r;
        const int col = nt * 128 + wn * 32 + ni * 16 + lr;
        const float g = accg[mi][ni][r], u = accu[mi][ni][r];
        const float vv = (g / (1.f + __expf(-g))) * u;
        act[(size_t)(e * CAPE + row) * I_DIM + col] = f2bf(vv);
      }
}

// ---------------- K4: down GEMM -> y (bf16) --------------------------------
// grid = E*MTMAX*16; block = 512 (8 waves, 2x4). Same pipeline.
__global__ __launch_bounds__(512) void k_down(const unsigned short* __restrict__ act,
                                              const float* __restrict__ wd,
                                              const int* __restrict__ cnts,
                                              unsigned short* __restrict__ y) {
  const int NB = NEXP * MTMAX * 16;
  const int v = (blockIdx.x & 7) * (NB / 8) + (blockIdx.x >> 3);
  const int e = v / (MTMAX * 16);
  const int rem = v % (MTMAX * 16);
  const int mt = rem / 16, nt = rem % 16;

  int cnt = cnts[e]; cnt = cnt < CAPE ? cnt : CAPE;
  if (cnt <= 0 || mt * 128 >= cnt) return;
  const int m0 = mt << 7;

  __shared__ __align__(16) short As[2][128 * LDW];
  __shared__ __align__(16) short Bt[2][128 * LDW];

  const int tid = threadIdx.x;
  const int lane = tid & 63, wave = tid >> 6;
  const int wm = wave >> 2, wn = wave & 3;
  const int lr = lane & 15, lg = lane >> 4;

  const int a_row = tid >> 2, a_ko = (tid & 3) * 8;   // 512 x 16B tasks
  const int b_kp = tid & 15, b_nq = tid >> 4;
  const int bk = 2 * b_kp, bn = 4 * b_nq;
  const size_t wbase = (size_t)e * I_DIM * H_DIM + (size_t)nt * 128;

  const unsigned short* ap = act + (size_t)(e * CAPE + m0 + a_row) * I_DIM + a_ko;
  const float* dp = wd + wbase + (size_t)bk * H_DIM + bn;

  f32x4 acc[4][2];
#pragma unroll
  for (int mi = 0; mi < 4; ++mi)
#pragma unroll
    for (int ni = 0; ni < 2; ++ni) acc[mi][ni] = (f32x4){0.f, 0.f, 0.f, 0.f};

  struct Tile { bf16x8 a; float4 d0, d1; };

  auto LOAD = [&](Tile& Tl, int kt) {
    const int k0 = kt * 32;
    Tl.a  = *(const bf16x8*)(ap + k0);
    Tl.d0 = *(const float4*)(dp + (size_t)k0 * H_DIM);
    Tl.d1 = *(const float4*)(dp + (size_t)k0 * H_DIM + H_DIM);
  };
  auto STORE = [&](const Tile& Tl, int b) {
    *(bf16x8*)(&As[b][a_row * LDW + a_ko]) = Tl.a;
    *(unsigned*)(&Bt[b][(bn + 0) * LDW + bk]) = pack2(Tl.d0.x, Tl.d1.x);
    *(unsigned*)(&Bt[b][(bn + 1) * LDW + bk]) = pack2(Tl.d0.y, Tl.d1.y);
    *(unsigned*)(&Bt[b][(bn + 2) * LDW + bk]) = pack2(Tl.d0.z, Tl.d1.z);
    *(unsigned*)(&Bt[b][(bn + 3) * LDW + bk]) = pack2(Tl.d0.w, Tl.d1.w);
  };
  auto COMPUTE = [&](int b) {
    bf16x8 a[4], bb[2];
#pragma unroll
    for (int mi = 0; mi < 4; ++mi)
      a[mi] = *(const bf16x8*)(&As[b][(wm * 64 + mi * 16 + lr) * LDW + lg * 8]);
#pragma unroll
    for (int ni = 0; ni < 2; ++ni)
      bb[ni] = *(const bf16x8*)(&Bt[b][(wn * 32 + ni * 16 + lr) * LDW + lg * 8]);
#pragma unroll
    for (int mi = 0; mi < 4; ++mi)
#pragma unroll
      for (int ni = 0; ni < 2; ++ni)
        acc[mi][ni] = __builtin_amdgcn_mfma_f32_16x16x32_bf16(a[mi], bb[ni], acc[mi][ni], 0, 0, 0);
  };

  const int NK = I_DIM / 32;   // 24, even
  Tile tA, tB;
  LOAD(tA, 0);
  STORE(tA, 0);
  LOAD(tB, 1);
  lds_barrier();

  int t = 0;
#pragma unroll 1
  for (; t + 2 < NK; t += 2) {
    LOAD(tA, t + 2);
    COMPUTE(0);
    STORE(tB, 1);
    lds_barrier();
    LOAD(tB, t + 3);
    COMPUTE(1);
    STORE(tA, 0);
    lds_barrier();
  }
  COMPUTE(0);
  STORE(tB, 1);
  lds_barrier();
  COMPUTE(1);

#pragma unroll
  for (int mi = 0; mi < 4; ++mi)
#pragma unroll
    for (int ni = 0; ni < 2; ++ni)
#pragma unroll
      for (int r = 0; r < 4; ++r) {
        const int row = m0 + wm * 64 + mi * 16 + lg * 4 + r;
        const int col = nt * 128 + wn * 32 + ni * 16 + lr;
        y[(size_t)(e * CAPE + row) * H_DIM + col] = f2bf(acc[mi][ni][r]);
      }
}

// ---------------- K5: combine (deterministic gather) -----------------------
__global__ __launch_bounds__(256) void k_combine(const unsigned short* __restrict__ y,
                                                 const int* __restrict__ topk_idx,
                                                 const float* __restrict__ topk_w,
                                                 const int* __restrict__ pair_pos,
                                                 float* __restrict__ out) {
  const int t = blockIdx.x;
  __shared__ int s_e[TOPK]; __shared__ int s_p[TOPK]; __shared__ float s_w[TOPK];
  if (threadIdx.x < TOPK) {
    s_e[threadIdx.x] = topk_idx[t * TOPK + threadIdx.x];
    s_p[threadIdx.x] = pair_pos[t * TOPK + threadIdx.x];
    s_w[threadIdx.x] = topk_w [t * TOPK + threadIdx.x];
  }
  __syncthreads();
  const int h0 = threadIdx.x * 8;
  float acc[8] = {0.f, 0.f, 0.f, 0.f, 0.f, 0.f, 0.f, 0.f};
#pragma unroll
  for (int k = 0; k < TOPK; ++k) {
    const int pos = s_p[k];
    if (pos >= CAPE) continue;
    const float w = s_w[k];
    const bf16x8 vv = *(const bf16x8*)(&y[(size_t)(s_e[k] * CAPE + pos) * H_DIM + h0]);
#pragma unroll
    for (int j = 0; j < 8; ++j) acc[j] += w * bf2f((unsigned short)vv[j]);
  }
  float4 o0 = {acc[0], acc[1], acc[2], acc[3]};
  float4 o1 = {acc[4], acc[5], acc[6], acc[7]};
  *(float4*)(out + (size_t)t * H_DIM + h0)     = o0;
  *(float4*)(out + (size_t)t * H_DIM + h0 + 4) = o1;
}

// ---------------------------------------------------------------------------
extern "C" void kernel_launch(void* const* d_in, const int* in_sizes, int n_in,
                              void* d_out, int out_size, void* d_ws, size_t ws_size,
                              hipStream_t stream) {
  const float* x   = (const float*)d_in[0];
  const float* wr  = (const float*)d_in[1];
  const float* wgt = (const float*)d_in[2];
  const float* wup = (const float*)d_in[3];
  const float* wdn = (const float*)d_in[4];
  float* out = (float*)d_out;

  char* ws = (char*)d_ws;
  int*            topk_idx   = (int*)(ws);                    //  64 KiB
  float*          topk_w     = (float*)(ws + 65536);          //  64 KiB
  int*            pair_pos   = (int*)(ws + 131072);           //  64 KiB
  int*            cnts       = (int*)(ws + 196608);           // 256 B
  int*            slot_token = (int*)(ws + 196864);           // 128 KiB
  unsigned short* act        = (unsigned short*)(ws + 327936);            // 48 MiB
  unsigned short* yb         = (unsigned short*)(ws + 327936 + 50331648); // 128 MiB

  k_router <<<dim3(T_TOK / 4),        dim3(256), 0, stream>>>(x, wr, topk_idx, topk_w);
  k_rank   <<<dim3(1),                dim3(256), 0, stream>>>(topk_idx, pair_pos, slot_token, cnts);
  k_gateup <<<dim3(NEXP * MTMAX * 6), dim3(512), 0, stream>>>(x, wgt, wup, slot_token, cnts, act);
  k_down   <<<dim3(NEXP * MTMAX * 16),dim3(512), 0, stream>>>(act, wdn, cnts, yb);
  k_combine<<<dim3(T_TOK),            dim3(256), 0, stream>>>(yb, topk_idx, topk_w, pair_pos, out);
}

// Round 7
// 835.042 us; speedup vs baseline: 1.3196x; 1.0839x over previous
//
#include <hip/hip_runtime.h>
#include <hip/hip_bf16.h>
#include <math.h>

// Problem constants (Qwen3 MoE block)
#define T_TOK 2048
#define H_DIM 2048
#define NEXP  64
#define TOPK  8
#define I_DIM 768
#define CAPE  512
#define MTMAX 4   // CAPE/128
#define LDW   40  // LDS row stride in shorts (80B)

typedef short bf16x8 __attribute__((ext_vector_type(8)));
typedef short bf16x4 __attribute__((ext_vector_type(4)));
typedef float f32x4  __attribute__((ext_vector_type(4)));

__device__ __forceinline__ unsigned short f2bf(float f) {
  unsigned u = __float_as_uint(f);
  u += 0x7fffu + ((u >> 16) & 1u);   // RNE
  return (unsigned short)(u >> 16);
}
__device__ __forceinline__ float bf2f(unsigned short b) {
  return __uint_as_float(((unsigned)b) << 16);
}
__device__ __forceinline__ unsigned pack2(float lo, float hi) {
  __hip_bfloat162 h = __float22bfloat162_rn(make_float2(lo, hi));  // v_cvt_pk_bf16_f32
  unsigned r; __builtin_memcpy(&r, &h, 4); return r;
}

// ---------------- K1: router logits + softmax-top8 + renorm ----------------
__global__ __launch_bounds__(256) void k_router(const float* __restrict__ x,
                                                const float* __restrict__ wr,
                                                int* __restrict__ topk_idx,
                                                float* __restrict__ topk_w) {
  const int lane = threadIdx.x & 63;
  const int t = blockIdx.x * 4 + (threadIdx.x >> 6);
  const float4* xr   = (const float4*)(x + (size_t)t * H_DIM);
  const float4* wrow = (const float4*)(wr + (size_t)lane * H_DIM);
  double acc = 0.0;                      // fp64: minimize top-k tie risk
  for (int i = 0; i < H_DIM / 4; ++i) {
    float4 a = xr[i], b = wrow[i];
    acc += (double)a.x * b.x; acc += (double)a.y * b.y;
    acc += (double)a.z * b.z; acc += (double)a.w * b.w;
  }
  float cur = (float)acc;
  float val[TOPK]; int idx[TOPK];
#pragma unroll
  for (int r = 0; r < TOPK; ++r) {
    float bv = cur; int bi = lane;
#pragma unroll
    for (int off = 32; off > 0; off >>= 1) {   // argmax, ties -> lower index
      float ov = __shfl_xor(bv, off);
      int   oi = __shfl_xor(bi, off);
      if (ov > bv || (ov == bv && oi < bi)) { bv = ov; bi = oi; }
    }
    val[r] = bv; idx[r] = bi;
    if (lane == bi) cur = -INFINITY;
  }
  float m = val[0], s = 0.f, w[TOPK];
#pragma unroll
  for (int r = 0; r < TOPK; ++r) { w[r] = expf(val[r] - m); s += w[r]; }
  if (lane < TOPK) {
    topk_idx[t * TOPK + lane] = idx[lane];
    topk_w [t * TOPK + lane] = w[lane] / s;
  }
}

// ---------------- K2: stable rank within expert ----------------------------
// Also records per-slot token id AND combine weight (for the fused epilogue).
__global__ __launch_bounds__(256) void k_rank(const int* __restrict__ topk_idx,
                                              const float* __restrict__ topk_w,
                                              int* __restrict__ slot_token,
                                              float* __restrict__ slot_w,
                                              int* __restrict__ cnts) {
  __shared__ int s_run[64];
  __shared__ int s_whist[4][64];
  const int tid = threadIdx.x, lane = tid & 63, wv = tid >> 6;
  if (tid < 64) s_run[tid] = 0;
  for (int c = 0; c < 64; ++c) {
    const int p = c * 256 + tid;
    const int e = topk_idx[p];
    __syncthreads();
    s_whist[wv][lane] = 0;
    __syncthreads();
    unsigned long long m = ~0ull;
#pragma unroll
    for (int b = 0; b < 6; ++b) {
      unsigned long long bb = __ballot((e >> b) & 1);
      m &= ((e >> b) & 1) ? bb : ~bb;
    }
    const int rw = __popcll(m & ((1ull << lane) - 1ull));
    if (rw == 0) s_whist[wv][e] = __popcll(m);
    __syncthreads();
    int r = rw;
    for (int w2 = 0; w2 < wv; ++w2) r += s_whist[w2][e];
    const int pos = s_run[e] + r;
    if (pos < CAPE) {
      slot_token[e * CAPE + pos] = p >> 3;
      slot_w   [e * CAPE + pos] = topk_w[p];
    }
    __syncthreads();
    if (tid < 64)
      s_run[tid] += s_whist[0][tid] + s_whist[1][tid] + s_whist[2][tid] + s_whist[3][tid];
  }
  __syncthreads();
  if (tid < 64) cnts[tid] = s_run[tid];
}

// ---------------- K3: fused gate+up GEMM + SwiGLU -> act (bf16) ------------
// grid = E*MTMAX*6; block = 512 (8 waves, 2x4). LDS dbuf + 2-deep reg rotation,
// ONE __syncthreads per k-step (round-3 champion structure: loads issued a full
// COMPUTE before the drain, compiler keeps scheduling freedom).
__global__ __launch_bounds__(512) void k_gateup(const float* __restrict__ x,
                                                const float* __restrict__ wg,
                                                const float* __restrict__ wu,
                                                const int* __restrict__ slot_token,
                                                const int* __restrict__ cnts,
                                                unsigned short* __restrict__ act) {
  const int NB = NEXP * MTMAX * 6;
  const int v = (blockIdx.x & 7) * (NB / 8) + (blockIdx.x >> 3);  // XCD chunk swizzle
  const int e = v / (MTMAX * 6);
  const int rem = v % (MTMAX * 6);
  const int mt = rem / 6, nt = rem % 6;

  int cnt = cnts[e]; cnt = cnt < CAPE ? cnt : CAPE;
  if (cnt <= 0 || mt * 128 >= cnt) return;
  const int m0 = mt << 7;

  __shared__ __align__(16) short As[2][128 * LDW];   // 20 KiB
  __shared__ __align__(16) short Bg[2][128 * LDW];   // 20 KiB
  __shared__ __align__(16) short Bu[2][128 * LDW];   // 20 KiB

  const int tid = threadIdx.x;
  const int lane = tid & 63, wave = tid >> 6;
  const int wm = wave >> 2, wn = wave & 3;       // 2x4 wave grid, 64x32 tiles
  const int lr = lane & 15, lg = lane >> 4;

  const int a_row0 = tid >> 3, a_kq = tid & 7;
  const int a_row1 = a_row0 + 64;
  const int b_kp = tid & 15, b_nq = tid >> 4;
  const int bk = 2 * b_kp, bn = 4 * b_nq;
  const size_t wbase = (size_t)e * H_DIM * I_DIM + (size_t)nt * 128;

  const int tok0 = (m0 + a_row0 < cnt) ? slot_token[e * CAPE + m0 + a_row0] : 0;
  const int tok1 = (m0 + a_row1 < cnt) ? slot_token[e * CAPE + m0 + a_row1] : 0;
  const float* xr0 = x + (size_t)tok0 * H_DIM + a_kq * 4;
  const float* xr1 = x + (size_t)tok1 * H_DIM + a_kq * 4;
  const float* gp  = wg + wbase + (size_t)bk * I_DIM + bn;
  const float* up  = wu + wbase + (size_t)bk * I_DIM + bn;

  f32x4 accg[4][2], accu[4][2];
#pragma unroll
  for (int mi = 0; mi < 4; ++mi)
#pragma unroll
    for (int ni = 0; ni < 2; ++ni) {
      accg[mi][ni] = (f32x4){0.f, 0.f, 0.f, 0.f};
      accu[mi][ni] = (f32x4){0.f, 0.f, 0.f, 0.f};
    }

  struct Tile { float4 a0, a1, g0, g1, u0, u1; };

  auto LOAD = [&](Tile& Tl, int kt) {
    const int k0 = kt * 32;
    Tl.a0 = *(const float4*)(xr0 + k0);
    Tl.a1 = *(const float4*)(xr1 + k0);
    Tl.g0 = *(const float4*)(gp + (size_t)k0 * I_DIM);
    Tl.g1 = *(const float4*)(gp + (size_t)k0 * I_DIM + I_DIM);
    Tl.u0 = *(const float4*)(up + (size_t)k0 * I_DIM);
    Tl.u1 = *(const float4*)(up + (size_t)k0 * I_DIM + I_DIM);
  };
  auto STORE = [&](const Tile& Tl, int b) {
    uint2 sa0 = { pack2(Tl.a0.x, Tl.a0.y), pack2(Tl.a0.z, Tl.a0.w) };
    uint2 sa1 = { pack2(Tl.a1.x, Tl.a1.y), pack2(Tl.a1.z, Tl.a1.w) };
    *(uint2*)(&As[b][a_row0 * LDW + a_kq * 4]) = sa0;
    *(uint2*)(&As[b][a_row1 * LDW + a_kq * 4]) = sa1;
    *(unsigned*)(&Bg[b][(bn + 0) * LDW + bk]) = pack2(Tl.g0.x, Tl.g1.x);
    *(unsigned*)(&Bg[b][(bn + 1) * LDW + bk]) = pack2(Tl.g0.y, Tl.g1.y);
    *(unsigned*)(&Bg[b][(bn + 2) * LDW + bk]) = pack2(Tl.g0.z, Tl.g1.z);
    *(unsigned*)(&Bg[b][(bn + 3) * LDW + bk]) = pack2(Tl.g0.w, Tl.g1.w);
    *(unsigned*)(&Bu[b][(bn + 0) * LDW + bk]) = pack2(Tl.u0.x, Tl.u1.x);
    *(unsigned*)(&Bu[b][(bn + 1) * LDW + bk]) = pack2(Tl.u0.y, Tl.u1.y);
    *(unsigned*)(&Bu[b][(bn + 2) * LDW + bk]) = pack2(Tl.u0.z, Tl.u1.z);
    *(unsigned*)(&Bu[b][(bn + 3) * LDW + bk]) = pack2(Tl.u0.w, Tl.u1.w);
  };
  auto COMPUTE = [&](int b) {
    bf16x8 a[4], bg[2], bu[2];
#pragma unroll
    for (int mi = 0; mi < 4; ++mi)
      a[mi] = *(const bf16x8*)(&As[b][(wm * 64 + mi * 16 + lr) * LDW + lg * 8]);
#pragma unroll
    for (int ni = 0; ni < 2; ++ni) {
      bg[ni] = *(const bf16x8*)(&Bg[b][(wn * 32 + ni * 16 + lr) * LDW + lg * 8]);
      bu[ni] = *(const bf16x8*)(&Bu[b][(wn * 32 + ni * 16 + lr) * LDW + lg * 8]);
    }
#pragma unroll
    for (int mi = 0; mi < 4; ++mi)
#pragma unroll
      for (int ni = 0; ni < 2; ++ni) {
        accg[mi][ni] = __builtin_amdgcn_mfma_f32_16x16x32_bf16(a[mi], bg[ni], accg[mi][ni], 0, 0, 0);
        accu[mi][ni] = __builtin_amdgcn_mfma_f32_16x16x32_bf16(a[mi], bu[ni], accu[mi][ni], 0, 0, 0);
      }
  };

  const int NK = H_DIM / 32;   // 64, even
  Tile tA, tB;
  LOAD(tA, 0);
  STORE(tA, 0);                 // waits only tA's loads
  LOAD(tB, 1);
  __syncthreads();

  int t = 0;
#pragma unroll 1
  for (; t + 2 < NK; t += 2) {
    LOAD(tA, t + 2);            // issued early: a full COMPUTE before the drain
    COMPUTE(0);                 // tile t
    STORE(tB, 1);               // tile t+1
    __syncthreads();
    LOAD(tB, t + 3);
    COMPUTE(1);                 // tile t+1
    STORE(tA, 0);               // tile t+2
    __syncthreads();
  }
  COMPUTE(0);                   // tile NK-2
  STORE(tB, 1);                 // tile NK-1
  __syncthreads();
  COMPUTE(1);                   // tile NK-1

  // epilogue: silu(g)*u -> bf16 act
#pragma unroll
  for (int mi = 0; mi < 4; ++mi)
#pragma unroll
    for (int ni = 0; ni < 2; ++ni)
#pragma unroll
      for (int r = 0; r < 4; ++r) {
        const int row = m0 + wm * 64 + mi * 16 + lg * 4 + r;
        const int col = nt * 128 + wn * 32 + ni * 16 + lr;
        const float g = accg[mi][ni][r], u = accu[mi][ni][r];
        const float vv = (g / (1.f + __expf(-g))) * u;
        act[(size_t)(e * CAPE + row) * I_DIM + col] = f2bf(vv);
      }
}

// ---------------- K4: down GEMM + fused weighted combine -> out ------------
// grid = E*MTMAX*16; block = 512 (8 waves, 2x4). Same pipeline as round 3;
// epilogue scatters w * y directly into out via HW fp32 atomics.
__global__ __launch_bounds__(512) void k_down(const unsigned short* __restrict__ act,
                                              const float* __restrict__ wd,
                                              const int* __restrict__ cnts,
                                              const int* __restrict__ slot_token,
                                              const float* __restrict__ slot_w,
                                              float* __restrict__ out) {
  const int NB = NEXP * MTMAX * 16;
  const int v = (blockIdx.x & 7) * (NB / 8) + (blockIdx.x >> 3);
  const int e = v / (MTMAX * 16);
  const int rem = v % (MTMAX * 16);
  const int mt = rem / 16, nt = rem % 16;

  int cnt = cnts[e]; cnt = cnt < CAPE ? cnt : CAPE;
  if (cnt <= 0 || mt * 128 >= cnt) return;
  const int m0 = mt << 7;

  __shared__ __align__(16) short As[2][128 * LDW];
  __shared__ __align__(16) short Bt[2][128 * LDW];

  const int tid = threadIdx.x;
  const int lane = tid & 63, wave = tid >> 6;
  const int wm = wave >> 2, wn = wave & 3;
  const int lr = lane & 15, lg = lane >> 4;

  const int a_row = tid >> 2, a_ko = (tid & 3) * 8;   // 512 x 16B tasks
  const int b_kp = tid & 15, b_nq = tid >> 4;
  const int bk = 2 * b_kp, bn = 4 * b_nq;
  const size_t wbase = (size_t)e * I_DIM * H_DIM + (size_t)nt * 128;

  const unsigned short* ap = act + (size_t)(e * CAPE + m0 + a_row) * I_DIM + a_ko;
  const float* dp = wd + wbase + (size_t)bk * H_DIM + bn;

  f32x4 acc[4][2];
#pragma unroll
  for (int mi = 0; mi < 4; ++mi)
#pragma unroll
    for (int ni = 0; ni < 2; ++ni) acc[mi][ni] = (f32x4){0.f, 0.f, 0.f, 0.f};

  struct Tile { bf16x8 a; float4 d0, d1; };

  auto LOAD = [&](Tile& Tl, int kt) {
    const int k0 = kt * 32;
    Tl.a  = *(const bf16x8*)(ap + k0);
    Tl.d0 = *(const float4*)(dp + (size_t)k0 * H_DIM);
    Tl.d1 = *(const float4*)(dp + (size_t)k0 * H_DIM + H_DIM);
  };
  auto STORE = [&](const Tile& Tl, int b) {
    *(bf16x8*)(&As[b][a_row * LDW + a_ko]) = Tl.a;
    *(unsigned*)(&Bt[b][(bn + 0) * LDW + bk]) = pack2(Tl.d0.x, Tl.d1.x);
    *(unsigned*)(&Bt[b][(bn + 1) * LDW + bk]) = pack2(Tl.d0.y, Tl.d1.y);
    *(unsigned*)(&Bt[b][(bn + 2) * LDW + bk]) = pack2(Tl.d0.z, Tl.d1.z);
    *(unsigned*)(&Bt[b][(bn + 3) * LDW + bk]) = pack2(Tl.d0.w, Tl.d1.w);
  };
  auto COMPUTE = [&](int b) {
    bf16x8 a[4], bb[2];
#pragma unroll
    for (int mi = 0; mi < 4; ++mi)
      a[mi] = *(const bf16x8*)(&As[b][(wm * 64 + mi * 16 + lr) * LDW + lg * 8]);
#pragma unroll
    for (int ni = 0; ni < 2; ++ni)
      bb[ni] = *(const bf16x8*)(&Bt[b][(wn * 32 + ni * 16 + lr) * LDW + lg * 8]);
#pragma unroll
    for (int mi = 0; mi < 4; ++mi)
#pragma unroll
      for (int ni = 0; ni < 2; ++ni)
        acc[mi][ni] = __builtin_amdgcn_mfma_f32_16x16x32_bf16(a[mi], bb[ni], acc[mi][ni], 0, 0, 0);
  };

  const int NK = I_DIM / 32;   // 24, even
  Tile tA, tB;
  LOAD(tA, 0);
  STORE(tA, 0);
  LOAD(tB, 1);
  __syncthreads();

  int t = 0;
#pragma unroll 1
  for (; t + 2 < NK; t += 2) {
    LOAD(tA, t + 2);
    COMPUTE(0);
    STORE(tB, 1);
    __syncthreads();
    LOAD(tB, t + 3);
    COMPUTE(1);
    STORE(tA, 0);
    __syncthreads();
  }
  COMPUTE(0);
  STORE(tB, 1);
  __syncthreads();
  COMPUTE(1);

  // fused combine epilogue: out[tok][col] += w * y  (HW fp32 atomics)
#pragma unroll
  for (int mi = 0; mi < 4; ++mi) {
#pragma unroll
    for (int r = 0; r < 4; ++r) {
      const int row = m0 + wm * 64 + mi * 16 + lg * 4 + r;
      if (row >= cnt) continue;                 // padded rows contribute nothing
      const int tok = slot_token[e * CAPE + row];
      const float w = slot_w[e * CAPE + row];
      float* orow = out + (size_t)tok * H_DIM + nt * 128 + wn * 32 + lr;
#pragma unroll
      for (int ni = 0; ni < 2; ++ni)
        unsafeAtomicAdd(orow + ni * 16, w * acc[mi][ni][r]);
    }
  }
}

// ---------------------------------------------------------------------------
extern "C" void kernel_launch(void* const* d_in, const int* in_sizes, int n_in,
                              void* d_out, int out_size, void* d_ws, size_t ws_size,
                              hipStream_t stream) {
  const float* x   = (const float*)d_in[0];
  const float* wr  = (const float*)d_in[1];
  const float* wgt = (const float*)d_in[2];
  const float* wup = (const float*)d_in[3];
  const float* wdn = (const float*)d_in[4];
  float* out = (float*)d_out;

  char* ws = (char*)d_ws;
  int*            topk_idx   = (int*)(ws);                    //  64 KiB
  float*          topk_w     = (float*)(ws + 65536);          //  64 KiB
  int*            cnts       = (int*)(ws + 131072);           // 256 B
  int*            slot_token = (int*)(ws + 131584);           // 128 KiB
  float*          slot_w     = (float*)(ws + 262656);         // 128 KiB
  unsigned short* act        = (unsigned short*)(ws + 524288);// 48 MiB

  hipMemsetAsync(out, 0, (size_t)out_size * sizeof(float), stream);
  k_router <<<dim3(T_TOK / 4),        dim3(256), 0, stream>>>(x, wr, topk_idx, topk_w);
  k_rank   <<<dim3(1),                dim3(256), 0, stream>>>(topk_idx, topk_w, slot_token, slot_w, cnts);
  k_gateup <<<dim3(NEXP * MTMAX * 6), dim3(512), 0, stream>>>(x, wgt, wup, slot_token, cnts, act);
  k_down   <<<dim3(NEXP * MTMAX * 16),dim3(512), 0, stream>>>(act, wdn, cnts, slot_token, slot_w, out);
}

// Round 8
// 833.608 us; speedup vs baseline: 1.3218x; 1.0017x over previous
//
#include <hip/hip_runtime.h>
#include <hip/hip_bf16.h>
#include <math.h>

// Problem constants (Qwen3 MoE block)
#define T_TOK 2048
#define H_DIM 2048
#define NEXP  64
#define TOPK  8
#define I_DIM 768
#define CAPE  512
#define MTMAX 4   // CAPE/128
#define LDW   40  // LDS row stride in shorts (80B)

typedef short bf16x8 __attribute__((ext_vector_type(8)));
typedef float f32x4  __attribute__((ext_vector_type(4)));

__device__ __forceinline__ unsigned short f2bf(float f) {
  unsigned u = __float_as_uint(f);
  u += 0x7fffu + ((u >> 16) & 1u);   // RNE
  return (unsigned short)(u >> 16);
}
__device__ __forceinline__ float bf2f(unsigned short b) {
  return __uint_as_float(((unsigned)b) << 16);
}
__device__ __forceinline__ unsigned pack2(float lo, float hi) {
  __hip_bfloat162 h = __float22bfloat162_rn(make_float2(lo, hi));  // v_cvt_pk_bf16_f32
  unsigned r; __builtin_memcpy(&r, &h, 4); return r;
}

// ---------------- K1: router logits + softmax-top8 + renorm ----------------
__global__ __launch_bounds__(256) void k_router(const float* __restrict__ x,
                                                const float* __restrict__ wr,
                                                int* __restrict__ topk_idx,
                                                float* __restrict__ topk_w) {
  const int lane = threadIdx.x & 63;
  const int t = blockIdx.x * 4 + (threadIdx.x >> 6);
  const float4* xr   = (const float4*)(x + (size_t)t * H_DIM);
  const float4* wrow = (const float4*)(wr + (size_t)lane * H_DIM);
  double acc = 0.0;                      // fp64: minimize top-k tie risk
  for (int i = 0; i < H_DIM / 4; ++i) {
    float4 a = xr[i], b = wrow[i];
    acc += (double)a.x * b.x; acc += (double)a.y * b.y;
    acc += (double)a.z * b.z; acc += (double)a.w * b.w;
  }
  float cur = (float)acc;
  float val[TOPK]; int idx[TOPK];
#pragma unroll
  for (int r = 0; r < TOPK; ++r) {
    float bv = cur; int bi = lane;
#pragma unroll
    for (int off = 32; off > 0; off >>= 1) {   // argmax, ties -> lower index
      float ov = __shfl_xor(bv, off);
      int   oi = __shfl_xor(bi, off);
      if (ov > bv || (ov == bv && oi < bi)) { bv = ov; bi = oi; }
    }
    val[r] = bv; idx[r] = bi;
    if (lane == bi) cur = -INFINITY;
  }
  float m = val[0], s = 0.f, w[TOPK];
#pragma unroll
  for (int r = 0; r < TOPK; ++r) { w[r] = expf(val[r] - m); s += w[r]; }
  if (lane < TOPK) {
    topk_idx[t * TOPK + lane] = idx[lane];
    topk_w [t * TOPK + lane] = w[lane] / s;
  }
}

// ---------------- K2: stable rank within expert ----------------------------
__global__ __launch_bounds__(256) void k_rank(const int* __restrict__ topk_idx,
                                              int* __restrict__ pair_pos,
                                              int* __restrict__ slot_token,
                                              int* __restrict__ cnts) {
  __shared__ int s_run[64];
  __shared__ int s_whist[4][64];
  const int tid = threadIdx.x, lane = tid & 63, wv = tid >> 6;
  if (tid < 64) s_run[tid] = 0;
  for (int c = 0; c < 64; ++c) {
    const int p = c * 256 + tid;
    const int e = topk_idx[p];
    __syncthreads();
    s_whist[wv][lane] = 0;
    __syncthreads();
    unsigned long long m = ~0ull;
#pragma unroll
    for (int b = 0; b < 6; ++b) {
      unsigned long long bb = __ballot((e >> b) & 1);
      m &= ((e >> b) & 1) ? bb : ~bb;
    }
    const int rw = __popcll(m & ((1ull << lane) - 1ull));
    if (rw == 0) s_whist[wv][e] = __popcll(m);
    __syncthreads();
    int r = rw;
    for (int w2 = 0; w2 < wv; ++w2) r += s_whist[w2][e];
    const int pos = s_run[e] + r;
    pair_pos[p] = pos;
    if (pos < CAPE) slot_token[e * CAPE + pos] = p >> 3;
    __syncthreads();
    if (tid < 64)
      s_run[tid] += s_whist[0][tid] + s_whist[1][tid] + s_whist[2][tid] + s_whist[3][tid];
  }
  __syncthreads();
  if (tid < 64) cnts[tid] = s_run[tid];
}

// ---------------- K3: fused gate+up GEMM + SwiGLU -> act (bf16) ------------
// Round-3 champion skeleton. New B staging: k-quad loads + conflict-free b64
// transpose writes (threads 0-255 stage Wg, 256-511 stage Wu).
__global__ __launch_bounds__(512) void k_gateup(const float* __restrict__ x,
                                                const float* __restrict__ wg,
                                                const float* __restrict__ wu,
                                                const int* __restrict__ slot_token,
                                                const int* __restrict__ cnts,
                                                unsigned short* __restrict__ act) {
  const int NB = NEXP * MTMAX * 6;
  const int v = (blockIdx.x & 7) * (NB / 8) + (blockIdx.x >> 3);  // XCD chunk swizzle
  const int e = v / (MTMAX * 6);
  const int rem = v % (MTMAX * 6);
  const int mt = rem / 6, nt = rem % 6;

  int cnt = cnts[e]; cnt = cnt < CAPE ? cnt : CAPE;
  if (cnt <= 0 || mt * 128 >= cnt) return;
  const int m0 = mt << 7;

  __shared__ __align__(16) short As[2][128 * LDW];   // 20 KiB
  __shared__ __align__(16) short Bg[2][128 * LDW];   // 20 KiB
  __shared__ __align__(16) short Bu[2][128 * LDW];   // 20 KiB

  const int tid = threadIdx.x;
  const int lane = tid & 63, wave = tid >> 6;
  const int wm = wave >> 2, wn = wave & 3;       // 2x4 wave grid, 64x32 tiles
  const int lr = lane & 15, lg = lane >> 4;

  // A staging: rows tid>>3 and +64, col-quad tid&7 (all 512 threads)
  const int a_row0 = tid >> 3, a_kq = tid & 7;
  const int a_row1 = a_row0 + 64;
  // B staging: one matrix per thread-half; k-quad kq = idx&7 (rows 4kq..+3),
  // col-quad nq = idx>>3 (cols 4nq..+3). kq-in-lane => conflict-free b64 writes.
  const int b_mat = tid >> 8;            // 0: gate, 1: up (wave-uniform)
  const int b_idx = tid & 255;
  const int b_kq = b_idx & 7, b_nq = b_idx >> 3;
  const size_t wbase = (size_t)e * H_DIM * I_DIM + (size_t)nt * 128;

  const int tok0 = (m0 + a_row0 < cnt) ? slot_token[e * CAPE + m0 + a_row0] : 0;
  const int tok1 = (m0 + a_row1 < cnt) ? slot_token[e * CAPE + m0 + a_row1] : 0;
  const float* xr0 = x + (size_t)tok0 * H_DIM + a_kq * 4;
  const float* xr1 = x + (size_t)tok1 * H_DIM + a_kq * 4;
  const float* bp  = (b_mat ? wu : wg) + wbase + (size_t)(4 * b_kq) * I_DIM + 4 * b_nq;
  short* Bdst0 = b_mat ? Bu[0] : Bg[0];
  short* Bdst1 = b_mat ? Bu[1] : Bg[1];

  f32x4 accg[4][2], accu[4][2];
#pragma unroll
  for (int mi = 0; mi < 4; ++mi)
#pragma unroll
    for (int ni = 0; ni < 2; ++ni) {
      accg[mi][ni] = (f32x4){0.f, 0.f, 0.f, 0.f};
      accu[mi][ni] = (f32x4){0.f, 0.f, 0.f, 0.f};
    }

  struct Tile { float4 a0, a1, b[4]; };

  auto LOAD = [&](Tile& Tl, int kt) {
    const int k0 = kt * 32;
    Tl.a0 = *(const float4*)(xr0 + k0);
    Tl.a1 = *(const float4*)(xr1 + k0);
    const float* r0 = bp + (size_t)k0 * I_DIM;
#pragma unroll
    for (int j = 0; j < 4; ++j)
      Tl.b[j] = *(const float4*)(r0 + (size_t)j * I_DIM);
  };
  auto STORE = [&](const Tile& Tl, int b) {
    uint2 sa0 = { pack2(Tl.a0.x, Tl.a0.y), pack2(Tl.a0.z, Tl.a0.w) };
    uint2 sa1 = { pack2(Tl.a1.x, Tl.a1.y), pack2(Tl.a1.z, Tl.a1.w) };
    *(uint2*)(&As[b][a_row0 * LDW + a_kq * 4]) = sa0;
    *(uint2*)(&As[b][a_row1 * LDW + a_kq * 4]) = sa1;
    short* Bd = b ? Bdst1 : Bdst0;
    const float* q0 = (const float*)&Tl.b[0];
    const float* q1 = (const float*)&Tl.b[1];
    const float* q2 = (const float*)&Tl.b[2];
    const float* q3 = (const float*)&Tl.b[3];
#pragma unroll
    for (int i = 0; i < 4; ++i) {
      uint2 w = { pack2(q0[i], q1[i]), pack2(q2[i], q3[i]) };  // k 4kq..4kq+3
      *(uint2*)(&Bd[(4 * b_nq + i) * LDW + 4 * b_kq]) = w;
    }
  };
  auto COMPUTE = [&](int b) {
    bf16x8 a[4], bg[2], bu[2];
#pragma unroll
    for (int mi = 0; mi < 4; ++mi)
      a[mi] = *(const bf16x8*)(&As[b][(wm * 64 + mi * 16 + lr) * LDW + lg * 8]);
#pragma unroll
    for (int ni = 0; ni < 2; ++ni) {
      bg[ni] = *(const bf16x8*)(&Bg[b][(wn * 32 + ni * 16 + lr) * LDW + lg * 8]);
      bu[ni] = *(const bf16x8*)(&Bu[b][(wn * 32 + ni * 16 + lr) * LDW + lg * 8]);
    }
#pragma unroll
    for (int mi = 0; mi < 4; ++mi)
#pragma unroll
      for (int ni = 0; ni < 2; ++ni) {
        accg[mi][ni] = __builtin_amdgcn_mfma_f32_16x16x32_bf16(a[mi], bg[ni], accg[mi][ni], 0, 0, 0);
        accu[mi][ni] = __builtin_amdgcn_mfma_f32_16x16x32_bf16(a[mi], bu[ni], accu[mi][ni], 0, 0, 0);
      }
  };

  const int NK = H_DIM / 32;   // 64, even
  Tile tA, tB;
  LOAD(tA, 0);
  STORE(tA, 0);                 // waits only tA's loads
  LOAD(tB, 1);
  __syncthreads();

  int t = 0;
#pragma unroll 1
  for (; t + 2 < NK; t += 2) {
    LOAD(tA, t + 2);            // issued early: a full COMPUTE before the drain
    COMPUTE(0);                 // tile t
    STORE(tB, 1);               // tile t+1
    __syncthreads();
    LOAD(tB, t + 3);
    COMPUTE(1);                 // tile t+1
    STORE(tA, 0);               // tile t+2
    __syncthreads();
  }
  COMPUTE(0);                   // tile NK-2
  STORE(tB, 1);                 // tile NK-1
  __syncthreads();
  COMPUTE(1);                   // tile NK-1

  // epilogue: silu(g)*u -> bf16 act
#pragma unroll
  for (int mi = 0; mi < 4; ++mi)
#pragma unroll
    for (int ni = 0; ni < 2; ++ni)
#pragma unroll
      for (int r = 0; r < 4; ++r) {
        const int row = m0 + wm * 64 + mi * 16 + lg * 4 + r;
        const int col = nt * 128 + wn * 32 + ni * 16 + lr;
        const float g = accg[mi][ni][r], u = accu[mi][ni][r];
        const float vv = (g / (1.f + __expf(-g))) * u;
        act[(size_t)(e * CAPE + row) * I_DIM + col] = f2bf(vv);
      }
}

// ---------------- K4: down GEMM -> y (bf16) --------------------------------
// Round-3 skeleton; B staging via k-quad float2 loads + conflict-free b64 writes.
__global__ __launch_bounds__(512) void k_down(const unsigned short* __restrict__ act,
                                              const float* __restrict__ wd,
                                              const int* __restrict__ cnts,
                                              unsigned short* __restrict__ y) {
  const int NB = NEXP * MTMAX * 16;
  const int v = (blockIdx.x & 7) * (NB / 8) + (blockIdx.x >> 3);
  const int e = v / (MTMAX * 16);
  const int rem = v % (MTMAX * 16);
  const int mt = rem / 16, nt = rem % 16;

  int cnt = cnts[e]; cnt = cnt < CAPE ? cnt : CAPE;
  if (cnt <= 0 || mt * 128 >= cnt) return;
  const int m0 = mt << 7;

  __shared__ __align__(16) short As[2][128 * LDW];
  __shared__ __align__(16) short Bt[2][128 * LDW];

  const int tid = threadIdx.x;
  const int lane = tid & 63, wave = tid >> 6;
  const int wm = wave >> 2, wn = wave & 3;
  const int lr = lane & 15, lg = lane >> 4;

  const int a_row = tid >> 2, a_ko = (tid & 3) * 8;   // 512 x 16B tasks
  // B: kq = tid&7 (rows 4kq..+3), nc = tid>>3 (0..63, cols 2nc..+1)
  const int b_kq = tid & 7, b_nc = tid >> 3;
  const size_t wbase = (size_t)e * I_DIM * H_DIM + (size_t)nt * 128;

  const unsigned short* ap = act + (size_t)(e * CAPE + m0 + a_row) * I_DIM + a_ko;
  const float* dp = wd + wbase + (size_t)(4 * b_kq) * H_DIM + 2 * b_nc;

  f32x4 acc[4][2];
#pragma unroll
  for (int mi = 0; mi < 4; ++mi)
#pragma unroll
    for (int ni = 0; ni < 2; ++ni) acc[mi][ni] = (f32x4){0.f, 0.f, 0.f, 0.f};

  struct Tile { bf16x8 a; float2 d[4]; };

  auto LOAD = [&](Tile& Tl, int kt) {
    const int k0 = kt * 32;
    Tl.a = *(const bf16x8*)(ap + k0);
    const float* r0 = dp + (size_t)k0 * H_DIM;
#pragma unroll
    for (int j = 0; j < 4; ++j)
      Tl.d[j] = *(const float2*)(r0 + (size_t)j * H_DIM);
  };
  auto STORE = [&](const Tile& Tl, int b) {
    *(bf16x8*)(&As[b][a_row * LDW + a_ko]) = Tl.a;
    const float* d0 = (const float*)&Tl.d[0];
    const float* d1 = (const float*)&Tl.d[1];
    const float* d2 = (const float*)&Tl.d[2];
    const float* d3 = (const float*)&Tl.d[3];
#pragma unroll
    for (int i = 0; i < 2; ++i) {
      uint2 w = { pack2(d0[i], d1[i]), pack2(d2[i], d3[i]) };   // k 4kq..4kq+3
      *(uint2*)(&Bt[b][(2 * b_nc + i) * LDW + 4 * b_kq]) = w;
    }
  };
  auto COMPUTE = [&](int b) {
    bf16x8 a[4], bb[2];
#pragma unroll
    for (int mi = 0; mi < 4; ++mi)
      a[mi] = *(const bf16x8*)(&As[b][(wm * 64 + mi * 16 + lr) * LDW + lg * 8]);
#pragma unroll
    for (int ni = 0; ni < 2; ++ni)
      bb[ni] = *(const bf16x8*)(&Bt[b][(wn * 32 + ni * 16 + lr) * LDW + lg * 8]);
#pragma unroll
    for (int mi = 0; mi < 4; ++mi)
#pragma unroll
      for (int ni = 0; ni < 2; ++ni)
        acc[mi][ni] = __builtin_amdgcn_mfma_f32_16x16x32_bf16(a[mi], bb[ni], acc[mi][ni], 0, 0, 0);
  };

  const int NK = I_DIM / 32;   // 24, even
  Tile tA, tB;
  LOAD(tA, 0);
  STORE(tA, 0);
  LOAD(tB, 1);
  __syncthreads();

  int t = 0;
#pragma unroll 1
  for (; t + 2 < NK; t += 2) {
    LOAD(tA, t + 2);
    COMPUTE(0);
    STORE(tB, 1);
    __syncthreads();
    LOAD(tB, t + 3);
    COMPUTE(1);
    STORE(tA, 0);
    __syncthreads();
  }
  COMPUTE(0);
  STORE(tB, 1);
  __syncthreads();
  COMPUTE(1);

#pragma unroll
  for (int mi = 0; mi < 4; ++mi)
#pragma unroll
    for (int ni = 0; ni < 2; ++ni)
#pragma unroll
      for (int r = 0; r < 4; ++r) {
        const int row = m0 + wm * 64 + mi * 16 + lg * 4 + r;
        const int col = nt * 128 + wn * 32 + ni * 16 + lr;
        y[(size_t)(e * CAPE + row) * H_DIM + col] = f2bf(acc[mi][ni][r]);
      }
}

// ---------------- K5: combine (deterministic gather) -----------------------
__global__ __launch_bounds__(256) void k_combine(const unsigned short* __restrict__ y,
                                                 const int* __restrict__ topk_idx,
                                                 const float* __restrict__ topk_w,
                                                 const int* __restrict__ pair_pos,
                                                 float* __restrict__ out) {
  const int t = blockIdx.x;
  __shared__ int s_e[TOPK]; __shared__ int s_p[TOPK]; __shared__ float s_w[TOPK];
  if (threadIdx.x < TOPK) {
    s_e[threadIdx.x] = topk_idx[t * TOPK + threadIdx.x];
    s_p[threadIdx.x] = pair_pos[t * TOPK + threadIdx.x];
    s_w[threadIdx.x] = topk_w [t * TOPK + threadIdx.x];
  }
  __syncthreads();
  const int h0 = threadIdx.x * 8;
  float acc[8] = {0.f, 0.f, 0.f, 0.f, 0.f, 0.f, 0.f, 0.f};
#pragma unroll
  for (int k = 0; k < TOPK; ++k) {
    const int pos = s_p[k];
    if (pos >= CAPE) continue;
    const float w = s_w[k];
    const bf16x8 vv = *(const bf16x8*)(&y[(size_t)(s_e[k] * CAPE + pos) * H_DIM + h0]);
#pragma unroll
    for (int j = 0; j < 8; ++j) acc[j] += w * bf2f((unsigned short)vv[j]);
  }
  float4 o0 = {acc[0], acc[1], acc[2], acc[3]};
  float4 o1 = {acc[4], acc[5], acc[6], acc[7]};
  *(float4*)(out + (size_t)t * H_DIM + h0)     = o0;
  *(float4*)(out + (size_t)t * H_DIM + h0 + 4) = o1;
}

// ---------------------------------------------------------------------------
extern "C" void kernel_launch(void* const* d_in, const int* in_sizes, int n_in,
                              void* d_out, int out_size, void* d_ws, size_t ws_size,
                              hipStream_t stream) {
  const float* x   = (const float*)d_in[0];
  const float* wr  = (const float*)d_in[1];
  const float* wgt = (const float*)d_in[2];
  const float* wup = (const float*)d_in[3];
  const float* wdn = (const float*)d_in[4];
  float* out = (float*)d_out;

  char* ws = (char*)d_ws;
  int*            topk_idx   = (int*)(ws);                    //  64 KiB
  float*          topk_w     = (float*)(ws + 65536);          //  64 KiB
  int*            pair_pos   = (int*)(ws + 131072);           //  64 KiB
  int*            cnts       = (int*)(ws + 196608);           // 256 B
  int*            slot_token = (int*)(ws + 196864);           // 128 KiB
  unsigned short* act        = (unsigned short*)(ws + 327936);            // 48 MiB
  unsigned short* yb         = (unsigned short*)(ws + 327936 + 50331648); // 128 MiB

  k_router <<<dim3(T_TOK / 4),        dim3(256), 0, stream>>>(x, wr, topk_idx, topk_w);
  k_rank   <<<dim3(1),                dim3(256), 0, stream>>>(topk_idx, pair_pos, slot_token, cnts);
  k_gateup <<<dim3(NEXP * MTMAX * 6), dim3(512), 0, stream>>>(x, wgt, wup, slot_token, cnts, act);
  k_down   <<<dim3(NEXP * MTMAX * 16),dim3(512), 0, stream>>>(act, wdn, cnts, yb);
  k_combine<<<dim3(T_TOK),            dim3(256), 0, stream>>>(yb, topk_idx, topk_w, pair_pos, out);
}